// Round 3
// baseline (180.728 us; speedup 1.0000x reference)
//
#include <hip/hip_runtime.h>

// RSI replicating jax-CPU cumsum via XLA ReduceWindowRewriter(base_length=16):
//   pad e[0..NP) with trailing zeros to 8192; reshape [512,16]
//   level-0: each 16-tile scanned SEQUENTIALLY; tile sums (512) -> recursively
//   [32,16] -> (32) -> [2,16] -> (2) -> len-2 scan; unwind adds ONE RN
//   exclusive outer offset per level.
//
// R1: LDS tile stride 16 -> 17 (bank conflicts 2.07e7 -> 2.33e6).
// R2: level-0 scan in regs; epilogue rcp-based (absmax unchanged).
// R3: eliminate the 70KB CG/CL LDS cumsum arrays entirely.
//   - phase C adds the exclusive tile offset IN REGISTERS (same single RN
//     add -> bit-identical cs values, now register-resident).
//   - phase D re-mapped: thread holding tile b computes outputs
//     o in [16b-(WM1-1), 16b+3]; cs[o+WM1-1] is own-tile, cs[o-1] is own
//     tile or the last WM1 values of tile b-1, fetched via __shfl_up(1)
//     (tile b-1 is lane-1 for both bi assignments) + a 7-slot LDS buffer
//     for wave-boundary tiles.
//   - WM1 is a TEMPLATE param: wm1 = COLS - outW is host-derivable from
//     out_size (8192-8179=13), so no runtime register indexing (rule:
//     runtime-indexed arrays spill to scratch). Generic wm1 falls back to
//     the proven R2 kernel (reads wsp on device).
//   LDS 79360 -> ~10.6KB; __launch_bounds__(256,4) -> 4 blocks/CU (was 2).
//   Stores are scalar dwords (row base odd -> float4 would be misaligned).

constexpr int ROWS = 2048;
constexpr int COLS = 8192;
constexpr int NP   = COLS - 1;   // 8191 p-values; padded to 8192
constexpr int BT   = 256;
constexpr int TS   = 17;         // padded tile stride (16 data + 1 pad)

// ---------------------------------------------------------------- R3 kernel
template<int WM1>
__global__ __launch_bounds__(BT, 4)
void rsi_reg_kernel(const float* __restrict__ x,
                    float* __restrict__ out,
                    int outW)
{
    // level-0 tile sums / level-1 scan values, padded: idx k -> k + (k>>4)
    __shared__ float T0g[544], T0l[544];
    __shared__ float S1g[544], S1l[544];
    __shared__ float T1g[32],  T1l[32];    // level-1 tile sums
    __shared__ float S2g[32],  S2l[32];    // level-2 scan values
    __shared__ float T2g[2],   T2l[2];     // level-2 tile sums
    __shared__ float S3g[2],   S3l[2];     // level-3 scan (len 2, naive)
    // wave-boundary prev-tile cs[16-WM1..15]:
    //  slots 0..3: tiles 63,127,191,255 (bi=0 writers t=63,127,191,255)
    //  slots 4..6: tiles 319,383,447    (bi=1 writers t=63,127,191)
    __shared__ float BPg[7][WM1], BPl[7][WM1];

    const int row  = blockIdx.x;
    const int t    = threadIdx.x;
    const int lane = t & 63;
    const float* __restrict__ xr = x + (size_t)row * COLS;

    float rg[2][16], rl[2][16];            // level-0 scan -> final cumsum

    // ---- phase A: elements + level-0 sequential 16-tile scans (regs only)
    #pragma unroll
    for (int bi = 0; bi < 2; ++bi) {
        const int b = t + 256 * bi;        // < 512
        const float4* xv = reinterpret_cast<const float4*>(xr + 16 * b);
        float xe[17];
        {
            float4 v0 = xv[0], v1 = xv[1], v2 = xv[2], v3 = xv[3];
            xe[0]=v0.x;  xe[1]=v0.y;  xe[2]=v0.z;  xe[3]=v0.w;
            xe[4]=v1.x;  xe[5]=v1.y;  xe[6]=v1.z;  xe[7]=v1.w;
            xe[8]=v2.x;  xe[9]=v2.y;  xe[10]=v2.z; xe[11]=v2.w;
            xe[12]=v3.x; xe[13]=v3.y; xe[14]=v3.z; xe[15]=v3.w;
        }
        xe[16] = (b < 511) ? xr[16 * b + 16] : 0.f;   // unused for j==NP

        float cg = 0.f, cl = 0.f;
        #pragma unroll
        for (int r = 0; r < 16; ++r) {
            const int j = 16 * b + r;
            float eg = 0.f, el = 0.f;
            if (j < NP) {
                const float prev = xe[r];
                const float nxt  = xe[r + 1];
                if (prev != 0.f) {
                    const float p = (nxt - prev) / prev;   // IEEE f32 div (exact)
                    eg = (p > 0.f) ?  p : 0.f;
                    el = (p < 0.f) ? -p : 0.f;
                }
            }
            cg = cg + eg;          // RN; trailing pad adds +0 (bit-neutral)
            cl = cl + el;
            rg[bi][r] = cg;
            rl[bi][r] = cl;
        }
        T0g[b + (b >> 4)] = cg;    // padded T0 index
        T0l[b + (b >> 4)] = cl;
    }
    __syncthreads();

    // ---- phase B1: level-1 sequential 16-tile scans over T0 (32 tiles)
    if (t < 32) {
        float cg = 0.f, cl = 0.f;
        for (int s = 0; s < 16; ++s) {
            const int k = TS * t + s;          // padded index of 16*t+s
            cg = cg + T0g[k];
            cl = cl + T0l[k];
            S1g[k] = cg;
            S1l[k] = cl;
        }
        T1g[t] = cg; T1l[t] = cl;
    }
    __syncthreads();

    // ---- phase B2: level-2 sequential 16-tile scans over T1 (2 tiles)
    if (t < 2) {
        float cg = 0.f, cl = 0.f;
        for (int u = 0; u < 16; ++u) {
            cg = cg + T1g[16 * t + u];
            cl = cl + T1l[16 * t + u];
            S2g[16 * t + u] = cg;
            S2l[16 * t + u] = cl;
        }
        T2g[t] = cg; T2l[t] = cl;
    }
    __syncthreads();

    // ---- phase B3: level-3 naive scan of T2 (len 2 <= base)
    if (t == 0) {
        S3g[0] = T2g[0]; S3g[1] = T2g[0] + T2g[1];
        S3l[0] = T2l[0]; S3l[1] = T2l[0] + T2l[1];
    }
    __syncthreads();
    // finalize S2: tile d=1 gets exclusive offset S3[0]
    if (t >= 16 && t < 32) {
        S2g[t] = S2g[t] + S3g[0];
        S2l[t] = S2l[t] + S3l[0];
    }
    __syncthreads();
    // finalize S1: tiles c>=1 get exclusive offset S2[c-1]
    for (int k = 16 + t; k < 512; k += BT) {
        const int c  = k >> 4;
        const int kp = k + (k >> 4);           // padded index
        S1g[kp] = S1g[kp] + S2g[c - 1];
        S1l[kp] = S1l[kp] + S2l[c - 1];
    }
    __syncthreads();

    // ---- phase C: finalize cumsum IN REGISTERS (single RN add, same op;
    //      b==0 adds +0.0 which is bit-neutral since scan values are >= +0)
    #pragma unroll
    for (int bi = 0; bi < 2; ++bi) {
        const int b = t + 256 * bi;
        float og = 0.f, ol = 0.f;
        if (b >= 1) {
            const int bp = (b - 1) + ((b - 1) >> 4);
            og = S1g[bp]; ol = S1l[bp];
        }
        #pragma unroll
        for (int r = 0; r < 16; ++r) {
            rg[bi][r] = rg[bi][r] + og;
            rl[bi][r] = rl[bi][r] + ol;
        }
    }
    // boundary export: last lane of each wave publishes its tiles' tail
    if (lane == 63) {
        const int w = t >> 6;                  // 0..3
        #pragma unroll
        for (int r = 16 - WM1; r < 16; ++r) {
            BPg[w][r - (16 - WM1)] = rg[0][r];
            BPl[w][r - (16 - WM1)] = rl[0][r];
        }
        if (w < 3) {
            #pragma unroll
            for (int r = 16 - WM1; r < 16; ++r) {
                BPg[4 + w][r - (16 - WM1)] = rg[1][r];
                BPl[4 + w][r - (16 - WM1)] = rl[1][r];
            }
        }
    }
    __syncthreads();

    // ---- phase D: epilogue. Thread holding tile b computes outputs
    //      o = 16b - (WM1-1) + k, k = 0..15  (clipped to [0, outW)).
    //      cs[o+WM1-1] = own rg[bi][k]; cs[o-1] = own (k>=WM1) or prev-tile
    //      tail pg[k] (k<WM1), fetched via shfl_up / boundary LDS.
    float* __restrict__ outr = out + (size_t)row * outW;
    #pragma unroll
    for (int bi = 0; bi < 2; ++bi) {
        const int b = t + 256 * bi;
        float pg[WM1], pl[WM1];
        #pragma unroll
        for (int r = 16 - WM1; r < 16; ++r) {
            pg[r - (16 - WM1)] = __shfl_up(rg[bi][r], 1);
            pl[r - (16 - WM1)] = __shfl_up(rl[bi][r], 1);
        }
        if (lane == 0) {
            int slot;
            if (bi == 0) slot = (t > 0) ? ((t >> 6) - 1) : -1;  // t==0: no prev
            else         slot = (t == 0) ? 3 : (3 + (t >> 6));
            if (slot >= 0) {
                #pragma unroll
                for (int q = 0; q < WM1; ++q) { pg[q] = BPg[slot][q]; pl[q] = BPl[slot][q]; }
            }
        }
        const int o0 = 16 * b - (WM1 - 1);
        #pragma unroll
        for (int k = 0; k < 16; ++k) {
            const int o = o0 + k;
            const float cg2 = rg[bi][k], cl2 = rl[bi][k];
            float cg1, cl1;
            if (k >= WM1) { cg1 = rg[bi][k - WM1]; cl1 = rl[bi][k - WM1]; }
            else          { cg1 = pg[k];           cl1 = pl[k]; }
            if (o < 1) { cg1 = 0.f; cl1 = 0.f; }   // o==0 uses zero prefix
            const float a  = cg2 - cg1;
            const float bb = cl2 - cl1;
            float rs = 0.f;
            if (bb != 0.f) rs = a * __builtin_amdgcn_rcpf(bb);
            const float v = 1.f - __builtin_amdgcn_rcpf(1.f + rs);
            if (o >= 0 && o < outW) outr[o] = v;
        }
    }
}

// ------------------------------------------------- generic fallback (== R2)
__global__ __launch_bounds__(BT, 1)
void rsi_rwr_fallback(const float* __restrict__ x,
                      const int* __restrict__ wsp,
                      float* __restrict__ out,
                      int outW)
{
    __shared__ float CG[512 * TS], CL[512 * TS];
    __shared__ float T0g[544], T0l[544];
    __shared__ float S1g[544], S1l[544];
    __shared__ float T1g[32],  T1l[32];
    __shared__ float S2g[32],  S2l[32];
    __shared__ float T2g[2],   T2l[2];
    __shared__ float S3g[2],   S3l[2];

    const int row = blockIdx.x;
    const int t   = threadIdx.x;
    const int wm1 = *wsp - 1;
    const float wf = (float)wm1;
    const float* __restrict__ xr = x + (size_t)row * COLS;

    float rg[2][16], rl[2][16];

    #pragma unroll
    for (int bi = 0; bi < 2; ++bi) {
        const int b = t + 256 * bi;
        const float4* xv = reinterpret_cast<const float4*>(xr + 16 * b);
        float xe[17];
        {
            float4 v0 = xv[0], v1 = xv[1], v2 = xv[2], v3 = xv[3];
            xe[0]=v0.x;  xe[1]=v0.y;  xe[2]=v0.z;  xe[3]=v0.w;
            xe[4]=v1.x;  xe[5]=v1.y;  xe[6]=v1.z;  xe[7]=v1.w;
            xe[8]=v2.x;  xe[9]=v2.y;  xe[10]=v2.z; xe[11]=v2.w;
            xe[12]=v3.x; xe[13]=v3.y; xe[14]=v3.z; xe[15]=v3.w;
        }
        xe[16] = (b < 511) ? xr[16 * b + 16] : 0.f;

        float cg = 0.f, cl = 0.f;
        #pragma unroll
        for (int r = 0; r < 16; ++r) {
            const int j = 16 * b + r;
            float eg = 0.f, el = 0.f;
            if (j < NP) {
                const float prev = xe[r];
                const float nxt  = xe[r + 1];
                if (prev != 0.f) {
                    const float p = (nxt - prev) / prev;
                    eg = (p > 0.f) ?  p : 0.f;
                    el = (p < 0.f) ? -p : 0.f;
                }
            }
            cg = cg + eg;
            cl = cl + el;
            rg[bi][r] = cg;
            rl[bi][r] = cl;
        }
        T0g[b + (b >> 4)] = cg;
        T0l[b + (b >> 4)] = cl;
    }
    __syncthreads();

    if (t < 32) {
        float cg = 0.f, cl = 0.f;
        for (int s = 0; s < 16; ++s) {
            const int k = TS * t + s;
            cg = cg + T0g[k];
            cl = cl + T0l[k];
            S1g[k] = cg;
            S1l[k] = cl;
        }
        T1g[t] = cg; T1l[t] = cl;
    }
    __syncthreads();

    if (t < 2) {
        float cg = 0.f, cl = 0.f;
        for (int u = 0; u < 16; ++u) {
            cg = cg + T1g[16 * t + u];
            cl = cl + T1l[16 * t + u];
            S2g[16 * t + u] = cg;
            S2l[16 * t + u] = cl;
        }
        T2g[t] = cg; T2l[t] = cl;
    }
    __syncthreads();

    if (t == 0) {
        S3g[0] = T2g[0]; S3g[1] = T2g[0] + T2g[1];
        S3l[0] = T2l[0]; S3l[1] = T2l[0] + T2l[1];
    }
    __syncthreads();
    if (t >= 16 && t < 32) {
        S2g[t] = S2g[t] + S3g[0];
        S2l[t] = S2l[t] + S3l[0];
    }
    __syncthreads();
    for (int k = 16 + t; k < 512; k += BT) {
        const int c  = k >> 4;
        const int kp = k + (k >> 4);
        S1g[kp] = S1g[kp] + S2g[c - 1];
        S1l[kp] = S1l[kp] + S2l[c - 1];
    }
    __syncthreads();

    #pragma unroll
    for (int bi = 0; bi < 2; ++bi) {
        const int b = t + 256 * bi;
        float og = 0.f, ol = 0.f;
        if (b >= 1) {
            const int bp = (b - 1) + ((b - 1) >> 4);
            og = S1g[bp]; ol = S1l[bp];
        }
        float* __restrict__ cgp = &CG[TS * b];
        float* __restrict__ clp = &CL[TS * b];
        #pragma unroll
        for (int r = 0; r < 16; ++r) {
            cgp[r] = rg[bi][r] + og;
            clp[r] = rl[bi][r] + ol;
        }
    }
    __syncthreads();

    float* __restrict__ outr = out + (size_t)row * outW;
    for (int o = t; o < outW; o += BT) {
        const int j2 = o + wm1 - 1;
        const int i2 = TS * (j2 >> 4) + (j2 & 15);
        float cg1 = 0.f, cl1 = 0.f;
        if (o >= 1) {
            const int j1 = o - 1;
            const int i1 = TS * (j1 >> 4) + (j1 & 15);
            cg1 = CG[i1];
            cl1 = CL[i1];
        }
        const float a  = CG[i2] - cg1;
        const float bb = CL[i2] - cl1;
        float rs = 0.f;
        if (bb != 0.f) rs = a * __builtin_amdgcn_rcpf(bb);
        outr[o] = 1.f - __builtin_amdgcn_rcpf(1.f + rs);
    }
}

extern "C" void kernel_launch(void* const* d_in, const int* in_sizes, int n_in,
                              void* d_out, int out_size, void* d_ws, size_t ws_size,
                              hipStream_t stream) {
    const float* x   = (const float*)d_in[0];
    const int*   wsp = (const int*)d_in[1];
    float*       out = (float*)d_out;

    const int outW = out_size / ROWS;   // 8179
    const int wm1  = COLS - outW;       // == window_size - 1 (host-derived)
    dim3 grid(ROWS);                    // one block per row
    dim3 block(BT);
    if (wm1 == 13) {
        rsi_reg_kernel<13><<<grid, block, 0, stream>>>(x, out, outW);
    } else {
        rsi_rwr_fallback<<<grid, block, 0, stream>>>(x, wsp, out, outW);
    }
}

// Round 4
// 178.968 us; speedup vs baseline: 1.0098x; 1.0098x over previous
//
#include <hip/hip_runtime.h>

// RSI replicating jax-CPU cumsum via XLA ReduceWindowRewriter(base_length=16):
//   pad e[0..NP) with trailing zeros to 8192; reshape [512,16]
//   level-0: each 16-tile scanned SEQUENTIALLY; tile sums (512) -> recursively
//   [32,16] -> (32) -> [2,16] -> (2) -> len-2 scan; unwind adds ONE RN
//   exclusive outer offset per level.
//
// R1: LDS tile stride 16 -> 17 (bank conflicts 2.07e7 -> 2.33e6).
// R2: level-0 scan in regs; epilogue rcp-based (absmax unchanged).
// R3: register-resident cumsum + shuffle epilogue. REGRESSED: 2 tiles/thread
//     needs ~100 live VGPRs in phase D; compiler allocated 56 + scratch
//     spills (VGPR_Count=56 < the 64 floats of rg/rl alone). 66 -> 102 us.
// R4: ONE tile per thread, 512-thread blocks (peak liveness ~75 VGPR, no
//     spill; launch_bounds(512,4) caps at 128). LDS stays ~10.2 KB ->
//     expect 2-3 blocks/CU = 16-24 waves/CU (was 8 in R2).
//     Barriers 7 -> 5: B3 + S2-finalize folded into S1-finalize
//     (off = S2raw[c-1] (+ T2g[0] if c-1>=16) -- same RN sequence as the
//     two-step original since S3g[0] was a bitwise copy of T2g[0]).

constexpr int ROWS = 2048;
constexpr int COLS = 8192;
constexpr int NP   = COLS - 1;   // 8191 p-values; padded to 8192
constexpr int BT   = 256;        // fallback block size
constexpr int BT4  = 512;        // R4 block size: one 16-tile per thread
constexpr int TS   = 17;         // padded tile stride (16 data + 1 pad)

// ---------------------------------------------------------------- R4 kernel
template<int WM1>
__global__ __launch_bounds__(BT4, 4)
void rsi_reg_kernel(const float* __restrict__ x,
                    float* __restrict__ out,
                    int outW)
{
    static_assert(WM1 >= 1 && WM1 <= 16, "phase-D mapping needs WM1<=16");
    // level-0 tile sums / level-1 scan values, padded: idx k -> k + (k>>4)
    __shared__ float T0g[544], T0l[544];
    __shared__ float S1g[544], S1l[544];
    __shared__ float T1g[32],  T1l[32];    // level-1 tile sums
    __shared__ float S2g[32],  S2l[32];    // level-2 scan values (raw)
    __shared__ float T2g[2],   T2l[2];     // level-2 tile sums (T2g[0]==S3g[0])
    // wave-boundary prev-tile cs[16-WM1..15]: slot w holds tile 64w+63
    // (written by lane 63 of wave w, read by lane 0 of wave w+1), w=0..6
    __shared__ float BPg[7][WM1], BPl[7][WM1];

    const int row  = blockIdx.x;
    const int t    = threadIdx.x;          // == tile index b, 0..511
    const int lane = t & 63;
    const int w    = t >> 6;               // wave id 0..7
    const float* __restrict__ xr = x + (size_t)row * COLS;

    float rg[16], rl[16];                  // level-0 scan -> final cumsum

    // ---- phase A: elements + level-0 sequential 16-tile scan (regs only)
    {
        const float4* xv = reinterpret_cast<const float4*>(xr + 16 * t);
        float xe[17];
        {
            float4 v0 = xv[0], v1 = xv[1], v2 = xv[2], v3 = xv[3];
            xe[0]=v0.x;  xe[1]=v0.y;  xe[2]=v0.z;  xe[3]=v0.w;
            xe[4]=v1.x;  xe[5]=v1.y;  xe[6]=v1.z;  xe[7]=v1.w;
            xe[8]=v2.x;  xe[9]=v2.y;  xe[10]=v2.z; xe[11]=v2.w;
            xe[12]=v3.x; xe[13]=v3.y; xe[14]=v3.z; xe[15]=v3.w;
        }
        xe[16] = (t < 511) ? xr[16 * t + 16] : 0.f;   // unused for j==NP

        float cg = 0.f, cl = 0.f;
        #pragma unroll
        for (int r = 0; r < 16; ++r) {
            const int j = 16 * t + r;
            float eg = 0.f, el = 0.f;
            if (j < NP) {
                const float prev = xe[r];
                const float nxt  = xe[r + 1];
                if (prev != 0.f) {
                    const float p = (nxt - prev) / prev;   // IEEE f32 div (exact)
                    eg = (p > 0.f) ?  p : 0.f;
                    el = (p < 0.f) ? -p : 0.f;
                }
            }
            cg = cg + eg;          // RN; trailing pad adds +0 (bit-neutral)
            cl = cl + el;
            rg[r] = cg;
            rl[r] = cl;
        }
        T0g[t + (t >> 4)] = cg;    // padded T0 index
        T0l[t + (t >> 4)] = cl;
    }
    __syncthreads();

    // ---- phase B1: level-1 sequential 16-tile scans over T0 (32 tiles)
    if (t < 32) {
        float cg = 0.f, cl = 0.f;
        for (int s = 0; s < 16; ++s) {
            const int k = TS * t + s;          // padded index of 16*t+s
            cg = cg + T0g[k];
            cl = cl + T0l[k];
            S1g[k] = cg;
            S1l[k] = cl;
        }
        T1g[t] = cg; T1l[t] = cl;
    }
    __syncthreads();

    // ---- phase B2: level-2 sequential 16-tile scans over T1 (2 tiles)
    if (t < 2) {
        float cg = 0.f, cl = 0.f;
        for (int u = 0; u < 16; ++u) {
            cg = cg + T1g[16 * t + u];
            cl = cl + T1l[16 * t + u];
            S2g[16 * t + u] = cg;              // raw (unfinalized) scan values
            S2l[16 * t + u] = cl;
        }
        T2g[t] = cg; T2l[t] = cl;              // T2g[0] == old S3g[0]
    }
    __syncthreads();

    // ---- fused B3 + S2-finalize + S1-finalize (bit-identical to the
    //      3-phase original: tmp = RN(S2raw + T2g[0]) == finalized S2,
    //      then S1 += tmp -- same RN adds, same order)
    if (t < 496) {
        const int k  = 16 + t;                 // 16..511
        const int c  = k >> 4;                 // 1..31
        const int kp = k + (k >> 4);           // padded index
        float og = S2g[c - 1], ol = S2l[c - 1];
        if (c - 1 >= 16) {                     // needs level-3 offset
            og = og + T2g[0];
            ol = ol + T2l[0];
        }
        S1g[kp] = S1g[kp] + og;
        S1l[kp] = S1l[kp] + ol;
    }
    __syncthreads();

    // ---- phase C: finalize cumsum IN REGISTERS (single RN add, same op;
    //      t==0 adds +0.0 which is bit-neutral since scan values are >= +0)
    {
        float og = 0.f, ol = 0.f;
        if (t >= 1) {
            const int bp = (t - 1) + ((t - 1) >> 4);
            og = S1g[bp]; ol = S1l[bp];
        }
        #pragma unroll
        for (int r = 0; r < 16; ++r) {
            rg[r] = rg[r] + og;
            rl[r] = rl[r] + ol;
        }
    }
    // boundary export: lane 63 of wave w publishes its tile tail for wave w+1
    if (lane == 63 && w < 7) {
        #pragma unroll
        for (int r = 16 - WM1; r < 16; ++r) {
            BPg[w][r - (16 - WM1)] = rg[r];
            BPl[w][r - (16 - WM1)] = rl[r];
        }
    }
    __syncthreads();

    // ---- phase D: epilogue. Thread b computes o = 16b-(WM1-1)+k, k=0..15.
    //      cs[o+WM1-1] = rg[k]; cs[o-1] = rg[k-WM1] (k>=WM1) or prev-tile
    //      tail pg[k] (k<WM1) via shfl_up(1) / boundary LDS for lane 0.
    float* __restrict__ outr = out + (size_t)row * outW;
    {
        float pg[WM1], pl[WM1];                // prev tile cs[16-WM1..15]
        #pragma unroll
        for (int r = 16 - WM1; r < 16; ++r) {
            pg[r - (16 - WM1)] = __shfl_up(rg[r], 1);
            pl[r - (16 - WM1)] = __shfl_up(rl[r], 1);
        }
        if (lane == 0 && w > 0) {
            #pragma unroll
            for (int q = 0; q < WM1; ++q) { pg[q] = BPg[w - 1][q]; pl[q] = BPl[w - 1][q]; }
        }
        const int o0 = 16 * t - (WM1 - 1);
        #pragma unroll
        for (int k = 0; k < 16; ++k) {
            const int o = o0 + k;
            const float cg2 = rg[k], cl2 = rl[k];
            float cg1, cl1;
            if (k >= WM1) { cg1 = rg[k - WM1]; cl1 = rl[k - WM1]; }
            else          { cg1 = pg[k];       cl1 = pl[k]; }
            if (o < 1) { cg1 = 0.f; cl1 = 0.f; }   // o==0 uses zero prefix
            const float a  = cg2 - cg1;
            const float bb = cl2 - cl1;
            float rs = 0.f;
            if (bb != 0.f) rs = a * __builtin_amdgcn_rcpf(bb);
            const float v = 1.f - __builtin_amdgcn_rcpf(1.f + rs);
            if ((unsigned)o < (unsigned)outW) outr[o] = v;
        }
    }
}

// ------------------------------------------------- generic fallback (== R2)
__global__ __launch_bounds__(BT, 1)
void rsi_rwr_fallback(const float* __restrict__ x,
                      const int* __restrict__ wsp,
                      float* __restrict__ out,
                      int outW)
{
    __shared__ float CG[512 * TS], CL[512 * TS];
    __shared__ float T0g[544], T0l[544];
    __shared__ float S1g[544], S1l[544];
    __shared__ float T1g[32],  T1l[32];
    __shared__ float S2g[32],  S2l[32];
    __shared__ float T2g[2],   T2l[2];
    __shared__ float S3g[2],   S3l[2];

    const int row = blockIdx.x;
    const int t   = threadIdx.x;
    const int wm1 = *wsp - 1;
    const float* __restrict__ xr = x + (size_t)row * COLS;

    float rg[2][16], rl[2][16];

    #pragma unroll
    for (int bi = 0; bi < 2; ++bi) {
        const int b = t + 256 * bi;
        const float4* xv = reinterpret_cast<const float4*>(xr + 16 * b);
        float xe[17];
        {
            float4 v0 = xv[0], v1 = xv[1], v2 = xv[2], v3 = xv[3];
            xe[0]=v0.x;  xe[1]=v0.y;  xe[2]=v0.z;  xe[3]=v0.w;
            xe[4]=v1.x;  xe[5]=v1.y;  xe[6]=v1.z;  xe[7]=v1.w;
            xe[8]=v2.x;  xe[9]=v2.y;  xe[10]=v2.z; xe[11]=v2.w;
            xe[12]=v3.x; xe[13]=v3.y; xe[14]=v3.z; xe[15]=v3.w;
        }
        xe[16] = (b < 511) ? xr[16 * b + 16] : 0.f;

        float cg = 0.f, cl = 0.f;
        #pragma unroll
        for (int r = 0; r < 16; ++r) {
            const int j = 16 * b + r;
            float eg = 0.f, el = 0.f;
            if (j < NP) {
                const float prev = xe[r];
                const float nxt  = xe[r + 1];
                if (prev != 0.f) {
                    const float p = (nxt - prev) / prev;
                    eg = (p > 0.f) ?  p : 0.f;
                    el = (p < 0.f) ? -p : 0.f;
                }
            }
            cg = cg + eg;
            cl = cl + el;
            rg[bi][r] = cg;
            rl[bi][r] = cl;
        }
        T0g[b + (b >> 4)] = cg;
        T0l[b + (b >> 4)] = cl;
    }
    __syncthreads();

    if (t < 32) {
        float cg = 0.f, cl = 0.f;
        for (int s = 0; s < 16; ++s) {
            const int k = TS * t + s;
            cg = cg + T0g[k];
            cl = cl + T0l[k];
            S1g[k] = cg;
            S1l[k] = cl;
        }
        T1g[t] = cg; T1l[t] = cl;
    }
    __syncthreads();

    if (t < 2) {
        float cg = 0.f, cl = 0.f;
        for (int u = 0; u < 16; ++u) {
            cg = cg + T1g[16 * t + u];
            cl = cl + T1l[16 * t + u];
            S2g[16 * t + u] = cg;
            S2l[16 * t + u] = cl;
        }
        T2g[t] = cg; T2l[t] = cl;
    }
    __syncthreads();

    if (t == 0) {
        S3g[0] = T2g[0]; S3g[1] = T2g[0] + T2g[1];
        S3l[0] = T2l[0]; S3l[1] = T2l[0] + T2l[1];
    }
    __syncthreads();
    if (t >= 16 && t < 32) {
        S2g[t] = S2g[t] + S3g[0];
        S2l[t] = S2l[t] + S3l[0];
    }
    __syncthreads();
    for (int k = 16 + t; k < 512; k += BT) {
        const int c  = k >> 4;
        const int kp = k + (k >> 4);
        S1g[kp] = S1g[kp] + S2g[c - 1];
        S1l[kp] = S1l[kp] + S2l[c - 1];
    }
    __syncthreads();

    #pragma unroll
    for (int bi = 0; bi < 2; ++bi) {
        const int b = t + 256 * bi;
        float og = 0.f, ol = 0.f;
        if (b >= 1) {
            const int bp = (b - 1) + ((b - 1) >> 4);
            og = S1g[bp]; ol = S1l[bp];
        }
        float* __restrict__ cgp = &CG[TS * b];
        float* __restrict__ clp = &CL[TS * b];
        #pragma unroll
        for (int r = 0; r < 16; ++r) {
            cgp[r] = rg[bi][r] + og;
            clp[r] = rl[bi][r] + ol;
        }
    }
    __syncthreads();

    float* __restrict__ outr = out + (size_t)row * outW;
    for (int o = t; o < outW; o += BT) {
        const int j2 = o + wm1 - 1;
        const int i2 = TS * (j2 >> 4) + (j2 & 15);
        float cg1 = 0.f, cl1 = 0.f;
        if (o >= 1) {
            const int j1 = o - 1;
            const int i1 = TS * (j1 >> 4) + (j1 & 15);
            cg1 = CG[i1];
            cl1 = CL[i1];
        }
        const float a  = CG[i2] - cg1;
        const float bb = CL[i2] - cl1;
        float rs = 0.f;
        if (bb != 0.f) rs = a * __builtin_amdgcn_rcpf(bb);
        outr[o] = 1.f - __builtin_amdgcn_rcpf(1.f + rs);
    }
}

extern "C" void kernel_launch(void* const* d_in, const int* in_sizes, int n_in,
                              void* d_out, int out_size, void* d_ws, size_t ws_size,
                              hipStream_t stream) {
    const float* x   = (const float*)d_in[0];
    const int*   wsp = (const int*)d_in[1];
    float*       out = (float*)d_out;

    const int outW = out_size / ROWS;   // 8179
    const int wm1  = COLS - outW;       // == window_size - 1 (host-derived)
    dim3 grid(ROWS);                    // one block per row
    if (wm1 == 13) {
        rsi_reg_kernel<13><<<grid, dim3(BT4), 0, stream>>>(x, out, outW);
    } else {
        rsi_rwr_fallback<<<grid, dim3(BT), 0, stream>>>(x, wsp, out, outW);
    }
}

// Round 5
// 119.960 us; speedup vs baseline: 1.5066x; 1.4919x over previous
//
#include <hip/hip_runtime.h>

// RSI replicating jax-CPU cumsum via XLA ReduceWindowRewriter(base_length=16):
//   pad e[0..NP) with trailing zeros to 8192; reshape [512,16]
//   level-0: each 16-tile scanned SEQUENTIALLY; tile sums (512) -> recursively
//   [32,16] -> (32) -> [2,16] -> (2) -> len-2 scan; unwind adds ONE RN
//   exclusive outer offset per level.
//
// R1: LDS tile stride 16 -> 17 (bank conflicts 2.07e7 -> 2.33e6).
// R2: level-0 scan in regs; epilogue rcp-based (absmax unchanged). 66us/disp.
// R3: register cumsum + shuffle epilogue, 2 tiles/thread. REGRESSED (102us).
// R4: 1 tile/thread, 512 threads. Still 98us. Diagnosis: phase D stores 16
//     CONSECUTIVE dwords per thread -> each wave store instr scatters over
//     64 cache lines (lane stride 64B) => ~27us/CU of TA address-coalescing
//     serialization vs R2's coalesced epilogue. WRITE_SIZE flat (L2 merges)
//     confirms it's issue cost, not HBM bytes.
// R5: keep register scan; fix the scatter:
//   (a) stage per-thread outputs in LDS XBUF[o+(o>>4)] (2-way banks, free),
//       barrier, then COALESCED global stores o = t + 512m.
//   (b) phase-D shuffles interleaved into the k-loop (no pg/pl[13] arrays
//       live; peak liveness ~40 VGPR).
//   (c) S1-finalize pass + barrier folded into phase C's offset read:
//       og = RN(S1raw + RN(S2raw[c-1] (+T2g[0] if c-1>=16))) -- identical
//       RN sequence to the separate pass -> bit-identical.
//   (d) B1 split gains/losses across 64 lanes (halves level-1 serial scan).
//   LDS ~44KB -> 3 blocks/CU (launch_bounds(512,6), VGPR cap 84, no spill).

constexpr int ROWS = 2048;
constexpr int COLS = 8192;
constexpr int NP   = COLS - 1;   // 8191 p-values; padded to 8192
constexpr int BT   = 256;        // fallback block size
constexpr int BT5  = 512;        // R5 block size: one 16-tile per thread
constexpr int TS   = 17;         // padded tile stride (16 data + 1 pad)

// ---------------------------------------------------------------- R5 kernel
template<int WM1>
__global__ __launch_bounds__(BT5, 6)
void rsi_reg_kernel(const float* __restrict__ x,
                    float* __restrict__ out,
                    int outW)
{
    static_assert(WM1 >= 1 && WM1 <= 16, "phase-D mapping needs WM1<=16");
    // output staging, padded addr = o + (o>>4); max idx 8178+511=8689
    __shared__ float XBUF[8704];
    // level-0 tile sums / level-1 scan values, padded: idx k -> k + (k>>4)
    __shared__ float T0g[544], T0l[544];
    __shared__ float S1g[544], S1l[544];   // RAW level-1 scan (never finalized)
    __shared__ float T1g[32],  T1l[32];    // level-1 tile sums
    __shared__ float S2g[32],  S2l[32];    // level-2 scan values (raw)
    __shared__ float T2g[2],   T2l[2];     // level-2 tile sums (T2g[0]==S3g[0])
    // wave-boundary prev-tile cs[16-WM1..15]: slot w holds tile 64w+63
    __shared__ float BPg[7][WM1], BPl[7][WM1];

    const int row  = blockIdx.x;
    const int t    = threadIdx.x;          // == tile index b, 0..511
    const int lane = t & 63;
    const int w    = t >> 6;               // wave id 0..7
    const float* __restrict__ xr = x + (size_t)row * COLS;

    float rg[16], rl[16];                  // level-0 scan -> final cumsum

    // ---- phase A: elements + level-0 sequential 16-tile scan (regs only)
    {
        const float4* xv = reinterpret_cast<const float4*>(xr + 16 * t);
        float xe[17];
        {
            float4 v0 = xv[0], v1 = xv[1], v2 = xv[2], v3 = xv[3];
            xe[0]=v0.x;  xe[1]=v0.y;  xe[2]=v0.z;  xe[3]=v0.w;
            xe[4]=v1.x;  xe[5]=v1.y;  xe[6]=v1.z;  xe[7]=v1.w;
            xe[8]=v2.x;  xe[9]=v2.y;  xe[10]=v2.z; xe[11]=v2.w;
            xe[12]=v3.x; xe[13]=v3.y; xe[14]=v3.z; xe[15]=v3.w;
        }
        xe[16] = (t < 511) ? xr[16 * t + 16] : 0.f;   // unused for j==NP

        float cg = 0.f, cl = 0.f;
        #pragma unroll
        for (int r = 0; r < 16; ++r) {
            const int j = 16 * t + r;
            float eg = 0.f, el = 0.f;
            if (j < NP) {
                const float prev = xe[r];
                const float nxt  = xe[r + 1];
                if (prev != 0.f) {
                    const float p = (nxt - prev) / prev;   // IEEE f32 div (exact)
                    eg = (p > 0.f) ?  p : 0.f;
                    el = (p < 0.f) ? -p : 0.f;
                }
            }
            cg = cg + eg;          // RN; trailing pad adds +0 (bit-neutral)
            cl = cl + el;
            rg[r] = cg;
            rl[r] = cl;
        }
        T0g[t + (t >> 4)] = cg;    // padded T0 index
        T0l[t + (t >> 4)] = cl;
    }
    __syncthreads();

    // ---- phase B1: level-1 sequential 16-tile scans over T0 (32 tiles),
    //      gains on lanes 0..31, losses on lanes 32..63 (independent chains)
    if (t < 64) {
        const int  tt  = t & 31;
        const bool isl = (t >= 32);
        const float* __restrict__ src  = isl ? T0l : T0g;
        float* __restrict__       dstS = isl ? S1l : S1g;
        float* __restrict__       dstT = isl ? T1l : T1g;
        float c = 0.f;
        for (int s = 0; s < 16; ++s) {
            const int k = TS * tt + s;         // padded index of 16*tt+s
            c = c + src[k];
            dstS[k] = c;                       // RAW scan value
        }
        dstT[tt] = c;
    }
    __syncthreads();

    // ---- phase B2: level-2 sequential 16-tile scans over T1 (2 tiles)
    if (t < 2) {
        float cg = 0.f, cl = 0.f;
        for (int u = 0; u < 16; ++u) {
            cg = cg + T1g[16 * t + u];
            cl = cl + T1l[16 * t + u];
            S2g[16 * t + u] = cg;              // raw scan values
            S2l[16 * t + u] = cl;
        }
        T2g[t] = cg; T2l[t] = cl;              // T2g[0] == old S3g[0]
    }
    __syncthreads();

    // ---- phase C: finalize cumsum IN REGISTERS.
    //      og = RN(S1raw[t-1] + RN(S2raw[c-1] (+ T2g[0] if c-1>=16)))
    //      == the old separate S2-finalize + S1-finalize RN sequence.
    //      Then rg += og (single RN add; t==0 adds +0.0, bit-neutral).
    {
        float og = 0.f, ol = 0.f;
        if (t >= 1) {
            const int bp = (t - 1) + ((t - 1) >> 4);
            og = S1g[bp]; ol = S1l[bp];        // raw level-1 scan
            const int c = (t - 1) >> 4;
            if (c >= 1) {
                float o2g = S2g[c - 1], o2l = S2l[c - 1];
                if (c - 1 >= 16) {             // level-3 offset (== S3g[0])
                    o2g = o2g + T2g[0];
                    o2l = o2l + T2l[0];
                }
                og = og + o2g;                 // RN(S1raw + finalizedS2)
                ol = ol + o2l;
            }
        }
        #pragma unroll
        for (int r = 0; r < 16; ++r) {
            rg[r] = rg[r] + og;
            rl[r] = rl[r] + ol;
        }
    }
    // boundary export: lane 63 of wave w publishes its tile tail for wave w+1
    if (lane == 63 && w < 7) {
        #pragma unroll
        for (int r = 16 - WM1; r < 16; ++r) {
            BPg[w][r - (16 - WM1)] = rg[r];
            BPl[w][r - (16 - WM1)] = rl[r];
        }
    }
    __syncthreads();

    // ---- phase D: compute 16 outputs, stage into XBUF (padded, 2-way banks)
    //      o = 16t-(WM1-1)+k; cs[o+WM1-1]=rg[k]; cs[o-1]=rg[k-WM1] (k>=WM1)
    //      or prev-tile tail via shfl_up(1) / BP for lane 0 (k<WM1).
    //      Shuffle is computed IN the k-iteration -> no live pg/pl arrays.
    {
        const int o0 = 16 * t - (WM1 - 1);
        #pragma unroll
        for (int k = 0; k < 16; ++k) {
            const int o = o0 + k;
            float cg1, cl1;
            if (k >= WM1) {
                cg1 = rg[k - WM1]; cl1 = rl[k - WM1];
            } else {
                cg1 = __shfl_up(rg[k + 16 - WM1], 1);
                cl1 = __shfl_up(rl[k + 16 - WM1], 1);
                if (lane == 0 && w > 0) {
                    cg1 = BPg[w - 1][k];
                    cl1 = BPl[w - 1][k];
                }
            }
            if (o < 1) { cg1 = 0.f; cl1 = 0.f; }   // o==0 uses zero prefix
            const float a  = rg[k] - cg1;
            const float bb = rl[k] - cl1;
            float rs = 0.f;
            if (bb != 0.f) rs = a * __builtin_amdgcn_rcpf(bb);
            const float v = 1.f - __builtin_amdgcn_rcpf(1.f + rs);
            if ((unsigned)o < (unsigned)outW) XBUF[o + (o >> 4)] = v;
        }
    }
    __syncthreads();

    // ---- phase E: coalesced readback + store
    float* __restrict__ outr = out + (size_t)row * outW;
    for (int o2 = t; o2 < outW; o2 += BT5) {
        outr[o2] = XBUF[o2 + (o2 >> 4)];
    }
}

// ------------------------------------------------- generic fallback (== R2)
__global__ __launch_bounds__(BT, 1)
void rsi_rwr_fallback(const float* __restrict__ x,
                      const int* __restrict__ wsp,
                      float* __restrict__ out,
                      int outW)
{
    __shared__ float CG[512 * TS], CL[512 * TS];
    __shared__ float T0g[544], T0l[544];
    __shared__ float S1g[544], S1l[544];
    __shared__ float T1g[32],  T1l[32];
    __shared__ float S2g[32],  S2l[32];
    __shared__ float T2g[2],   T2l[2];
    __shared__ float S3g[2],   S3l[2];

    const int row = blockIdx.x;
    const int t   = threadIdx.x;
    const int wm1 = *wsp - 1;
    const float* __restrict__ xr = x + (size_t)row * COLS;

    float rg[2][16], rl[2][16];

    #pragma unroll
    for (int bi = 0; bi < 2; ++bi) {
        const int b = t + 256 * bi;
        const float4* xv = reinterpret_cast<const float4*>(xr + 16 * b);
        float xe[17];
        {
            float4 v0 = xv[0], v1 = xv[1], v2 = xv[2], v3 = xv[3];
            xe[0]=v0.x;  xe[1]=v0.y;  xe[2]=v0.z;  xe[3]=v0.w;
            xe[4]=v1.x;  xe[5]=v1.y;  xe[6]=v1.z;  xe[7]=v1.w;
            xe[8]=v2.x;  xe[9]=v2.y;  xe[10]=v2.z; xe[11]=v2.w;
            xe[12]=v3.x; xe[13]=v3.y; xe[14]=v3.z; xe[15]=v3.w;
        }
        xe[16] = (b < 511) ? xr[16 * b + 16] : 0.f;

        float cg = 0.f, cl = 0.f;
        #pragma unroll
        for (int r = 0; r < 16; ++r) {
            const int j = 16 * b + r;
            float eg = 0.f, el = 0.f;
            if (j < NP) {
                const float prev = xe[r];
                const float nxt  = xe[r + 1];
                if (prev != 0.f) {
                    const float p = (nxt - prev) / prev;
                    eg = (p > 0.f) ?  p : 0.f;
                    el = (p < 0.f) ? -p : 0.f;
                }
            }
            cg = cg + eg;
            cl = cl + el;
            rg[bi][r] = cg;
            rl[bi][r] = cl;
        }
        T0g[b + (b >> 4)] = cg;
        T0l[b + (b >> 4)] = cl;
    }
    __syncthreads();

    if (t < 32) {
        float cg = 0.f, cl = 0.f;
        for (int s = 0; s < 16; ++s) {
            const int k = TS * t + s;
            cg = cg + T0g[k];
            cl = cl + T0l[k];
            S1g[k] = cg;
            S1l[k] = cl;
        }
        T1g[t] = cg; T1l[t] = cl;
    }
    __syncthreads();

    if (t < 2) {
        float cg = 0.f, cl = 0.f;
        for (int u = 0; u < 16; ++u) {
            cg = cg + T1g[16 * t + u];
            cl = cl + T1l[16 * t + u];
            S2g[16 * t + u] = cg;
            S2l[16 * t + u] = cl;
        }
        T2g[t] = cg; T2l[t] = cl;
    }
    __syncthreads();

    if (t == 0) {
        S3g[0] = T2g[0]; S3g[1] = T2g[0] + T2g[1];
        S3l[0] = T2l[0]; S3l[1] = T2l[0] + T2l[1];
    }
    __syncthreads();
    if (t >= 16 && t < 32) {
        S2g[t] = S2g[t] + S3g[0];
        S2l[t] = S2l[t] + S3l[0];
    }
    __syncthreads();
    for (int k = 16 + t; k < 512; k += BT) {
        const int c  = k >> 4;
        const int kp = k + (k >> 4);
        S1g[kp] = S1g[kp] + S2g[c - 1];
        S1l[kp] = S1l[kp] + S2l[c - 1];
    }
    __syncthreads();

    #pragma unroll
    for (int bi = 0; bi < 2; ++bi) {
        const int b = t + 256 * bi;
        float og = 0.f, ol = 0.f;
        if (b >= 1) {
            const int bp = (b - 1) + ((b - 1) >> 4);
            og = S1g[bp]; ol = S1l[bp];
        }
        float* __restrict__ cgp = &CG[TS * b];
        float* __restrict__ clp = &CL[TS * b];
        #pragma unroll
        for (int r = 0; r < 16; ++r) {
            cgp[r] = rg[bi][r] + og;
            clp[r] = rl[bi][r] + ol;
        }
    }
    __syncthreads();

    float* __restrict__ outr = out + (size_t)row * outW;
    for (int o = t; o < outW; o += BT) {
        const int j2 = o + wm1 - 1;
        const int i2 = TS * (j2 >> 4) + (j2 & 15);
        float cg1 = 0.f, cl1 = 0.f;
        if (o >= 1) {
            const int j1 = o - 1;
            const int i1 = TS * (j1 >> 4) + (j1 & 15);
            cg1 = CG[i1];
            cl1 = CL[i1];
        }
        const float a  = CG[i2] - cg1;
        const float bb = CL[i2] - cl1;
        float rs = 0.f;
        if (bb != 0.f) rs = a * __builtin_amdgcn_rcpf(bb);
        outr[o] = 1.f - __builtin_amdgcn_rcpf(1.f + rs);
    }
}

extern "C" void kernel_launch(void* const* d_in, const int* in_sizes, int n_in,
                              void* d_out, int out_size, void* d_ws, size_t ws_size,
                              hipStream_t stream) {
    const float* x   = (const float*)d_in[0];
    const int*   wsp = (const int*)d_in[1];
    float*       out = (float*)d_out;

    const int outW = out_size / ROWS;   // 8179
    const int wm1  = COLS - outW;       // == window_size - 1 (host-derived)
    dim3 grid(ROWS);                    // one block per row
    if (wm1 == 13) {
        rsi_reg_kernel<13><<<grid, dim3(BT5), 0, stream>>>(x, out, outW);
    } else {
        rsi_rwr_fallback<<<grid, dim3(BT), 0, stream>>>(x, wsp, out, outW);
    }
}

// Round 6
// 118.964 us; speedup vs baseline: 1.5192x; 1.0084x over previous
//
#include <hip/hip_runtime.h>

// RSI replicating jax-CPU cumsum via XLA ReduceWindowRewriter(base_length=16):
//   pad e[0..NP) with trailing zeros to 8192; reshape [512,16]
//   level-0: each 16-tile scanned SEQUENTIALLY; tile sums (512) -> recursively
//   [32,16] -> (32) -> [2,16] -> (2) -> len-2 scan; unwind adds ONE RN
//   exclusive outer offset per level.
//
// R1: LDS tile stride 16 -> 17 (bank conflicts 2.07e7 -> 2.33e6).
// R2: level-0 scan in regs; epilogue rcp-based (absmax unchanged). 66us/disp.
// R3/R4: register cumsum, 1 tile/thread. Store scatter (16 consecutive
//     dwords/thread -> 64 lines per wave-store) kept it at ~98us.
// R5: outputs staged through padded LDS XBUF -> coalesced stores. ~38us.
// R6: same cure for the LOAD side + LDS lifetime aliasing:
//   (a) phase A0: stage the input row into LDS with ideally-coalesced
//       float4 loads (lane-stride 16B -> 16 segments/instr, vs phase A's
//       old lane-stride-64B pattern = 64 segments/instr, ~8.5us/CU of TA
//       serialization). Stage pad: 4 floats per 64 (16B alignment kept;
//       phase-A re-reads are <=4-way bank conflicts - cheap).
//   (b) ONE aliased buffer SH[8704] holds, in disjoint lifetimes:
//       staged input (A0..A) -> S1g/S1l raw level-1 scan (B1..C) ->
//       XBUF output stage (D..E). Barriers separate all three.
//       LDS 44.4KB -> ~39.5KB; if VGPR lands <=64, 4 blocks/CU come free.
//   All arithmetic (order, operands, RN) untouched -> bit-identical output.

constexpr int ROWS = 2048;
constexpr int COLS = 8192;
constexpr int NP   = COLS - 1;   // 8191 p-values; padded to 8192
constexpr int BT   = 256;        // fallback block size
constexpr int BT6  = 512;        // one 16-tile per thread
constexpr int TS   = 17;         // padded tile stride (16 data + 1 pad)

__device__ __forceinline__ int sidx(int f) {   // stage pad: +4 floats per 64
    return f + ((f >> 6) << 2);
}

// ---------------------------------------------------------------- R6 kernel
template<int WM1>
__global__ __launch_bounds__(BT6, 6)
void rsi_reg_kernel(const float* __restrict__ x,
                    float* __restrict__ out,
                    int outW)
{
    static_assert(WM1 >= 1 && WM1 <= 16, "phase-D mapping needs WM1<=16");
    // Multi-lifetime buffer:
    //   A0..A : staged input row, addr sidx(f), max 8191+508=8699
    //   B1..C : S1g = SH[0..544), S1l = SH[544..1088)  (raw level-1 scan)
    //   D..E  : XBUF, addr o + (o>>4), max 8178+511=8689
    __shared__ float SH[8704];
    __shared__ float T0g[544], T0l[544];   // level-0 tile sums (padded idx)
    __shared__ float T1g[32],  T1l[32];    // level-1 tile sums
    __shared__ float S2g[32],  S2l[32];    // level-2 scan values (raw)
    __shared__ float T2g[2],   T2l[2];     // level-2 tile sums (T2g[0]==S3g[0])
    // wave-boundary prev-tile cs[16-WM1..15]: slot w holds tile 64w+63
    __shared__ float BPg[7][WM1], BPl[7][WM1];

    float* const S1g = SH;                 // aliased lifetimes (see above)
    float* const S1l = SH + 544;

    const int row  = blockIdx.x;
    const int t    = threadIdx.x;          // == tile index b, 0..511
    const int lane = t & 63;
    const int w    = t >> 6;               // wave id 0..7
    const float* __restrict__ xr = x + (size_t)row * COLS;

    float rg[16], rl[16];                  // level-0 scan -> final cumsum

    // ---- phase A0: stage row into LDS, ideally coalesced
    #pragma unroll
    for (int m = 0; m < 4; ++m) {
        const int f = 4 * (t + 512 * m);   // f%4==0; f..f+3 in one 64-group
        const float4 v = *reinterpret_cast<const float4*>(xr + f);
        *reinterpret_cast<float4*>(&SH[sidx(f)]) = v;
    }
    __syncthreads();

    // ---- phase A: elements + level-0 sequential 16-tile scan (regs only)
    {
        float xe[17];
        {
            const int base = sidx(16 * t); // 16t..16t+15 share one 64-group
            #pragma unroll
            for (int q = 0; q < 4; ++q) {
                const float4 v = *reinterpret_cast<const float4*>(&SH[base + 4 * q]);
                xe[4*q+0]=v.x; xe[4*q+1]=v.y; xe[4*q+2]=v.z; xe[4*q+3]=v.w;
            }
            xe[16] = (t < 511) ? SH[sidx(16 * t + 16)] : 0.f; // unused j==NP
        }

        float cg = 0.f, cl = 0.f;
        #pragma unroll
        for (int r = 0; r < 16; ++r) {
            const int j = 16 * t + r;
            float eg = 0.f, el = 0.f;
            if (j < NP) {
                const float prev = xe[r];
                const float nxt  = xe[r + 1];
                if (prev != 0.f) {
                    const float p = (nxt - prev) / prev;   // IEEE f32 div (exact)
                    eg = (p > 0.f) ?  p : 0.f;
                    el = (p < 0.f) ? -p : 0.f;
                }
            }
            cg = cg + eg;          // RN; trailing pad adds +0 (bit-neutral)
            cl = cl + el;
            rg[r] = cg;
            rl[r] = cl;
        }
        T0g[t + (t >> 4)] = cg;    // padded T0 index
        T0l[t + (t >> 4)] = cl;
    }
    __syncthreads();               // staged input dead; SH becomes S1

    // ---- phase B1: level-1 sequential 16-tile scans over T0 (32 tiles),
    //      gains on lanes 0..31, losses on lanes 32..63 (independent chains)
    if (t < 64) {
        const int  tt  = t & 31;
        const bool isl = (t >= 32);
        const float* __restrict__ src  = isl ? T0l : T0g;
        float* __restrict__       dstS = isl ? S1l : S1g;
        float* __restrict__       dstT = isl ? T1l : T1g;
        float c = 0.f;
        for (int s = 0; s < 16; ++s) {
            const int k = TS * tt + s;         // padded index of 16*tt+s
            c = c + src[k];
            dstS[k] = c;                       // RAW scan value
        }
        dstT[tt] = c;
    }
    __syncthreads();

    // ---- phase B2: level-2 sequential 16-tile scans over T1 (2 tiles)
    if (t < 2) {
        float cg = 0.f, cl = 0.f;
        for (int u = 0; u < 16; ++u) {
            cg = cg + T1g[16 * t + u];
            cl = cl + T1l[16 * t + u];
            S2g[16 * t + u] = cg;              // raw scan values
            S2l[16 * t + u] = cl;
        }
        T2g[t] = cg; T2l[t] = cl;              // T2g[0] == old S3g[0]
    }
    __syncthreads();

    // ---- phase C: finalize cumsum IN REGISTERS.
    //      og = RN(S1raw[t-1] + RN(S2raw[c-1] (+ T2g[0] if c-1>=16)))
    //      == the old separate S2-finalize + S1-finalize RN sequence.
    //      Then rg += og (single RN add; t==0 adds +0.0, bit-neutral).
    {
        float og = 0.f, ol = 0.f;
        if (t >= 1) {
            const int bp = (t - 1) + ((t - 1) >> 4);
            og = S1g[bp]; ol = S1l[bp];        // raw level-1 scan
            const int c = (t - 1) >> 4;
            if (c >= 1) {
                float o2g = S2g[c - 1], o2l = S2l[c - 1];
                if (c - 1 >= 16) {             // level-3 offset (== S3g[0])
                    o2g = o2g + T2g[0];
                    o2l = o2l + T2l[0];
                }
                og = og + o2g;                 // RN(S1raw + finalizedS2)
                ol = ol + o2l;
            }
        }
        #pragma unroll
        for (int r = 0; r < 16; ++r) {
            rg[r] = rg[r] + og;
            rl[r] = rl[r] + ol;
        }
    }
    // boundary export: lane 63 of wave w publishes its tile tail for wave w+1
    if (lane == 63 && w < 7) {
        #pragma unroll
        for (int r = 16 - WM1; r < 16; ++r) {
            BPg[w][r - (16 - WM1)] = rg[r];
            BPl[w][r - (16 - WM1)] = rl[r];
        }
    }
    __syncthreads();               // S1 dead; SH becomes XBUF

    // ---- phase D: compute 16 outputs, stage into SH (padded, 2-way banks)
    //      o = 16t-(WM1-1)+k; cs[o+WM1-1]=rg[k]; cs[o-1]=rg[k-WM1] (k>=WM1)
    //      or prev-tile tail via shfl_up(1) / BP for lane 0 (k<WM1).
    {
        const int o0 = 16 * t - (WM1 - 1);
        #pragma unroll
        for (int k = 0; k < 16; ++k) {
            const int o = o0 + k;
            float cg1, cl1;
            if (k >= WM1) {
                cg1 = rg[k - WM1]; cl1 = rl[k - WM1];
            } else {
                cg1 = __shfl_up(rg[k + 16 - WM1], 1);
                cl1 = __shfl_up(rl[k + 16 - WM1], 1);
                if (lane == 0 && w > 0) {
                    cg1 = BPg[w - 1][k];
                    cl1 = BPl[w - 1][k];
                }
            }
            if (o < 1) { cg1 = 0.f; cl1 = 0.f; }   // o==0 uses zero prefix
            const float a  = rg[k] - cg1;
            const float bb = rl[k] - cl1;
            float rs = 0.f;
            if (bb != 0.f) rs = a * __builtin_amdgcn_rcpf(bb);
            const float v = 1.f - __builtin_amdgcn_rcpf(1.f + rs);
            if ((unsigned)o < (unsigned)outW) SH[o + (o >> 4)] = v;
        }
    }
    __syncthreads();

    // ---- phase E: coalesced readback + store
    float* __restrict__ outr = out + (size_t)row * outW;
    for (int o2 = t; o2 < outW; o2 += BT6) {
        outr[o2] = SH[o2 + (o2 >> 4)];
    }
}

// ------------------------------------------------- generic fallback (== R2)
__global__ __launch_bounds__(BT, 1)
void rsi_rwr_fallback(const float* __restrict__ x,
                      const int* __restrict__ wsp,
                      float* __restrict__ out,
                      int outW)
{
    __shared__ float CG[512 * TS], CL[512 * TS];
    __shared__ float T0g[544], T0l[544];
    __shared__ float S1g[544], S1l[544];
    __shared__ float T1g[32],  T1l[32];
    __shared__ float S2g[32],  S2l[32];
    __shared__ float T2g[2],   T2l[2];
    __shared__ float S3g[2],   S3l[2];

    const int row = blockIdx.x;
    const int t   = threadIdx.x;
    const int wm1 = *wsp - 1;
    const float* __restrict__ xr = x + (size_t)row * COLS;

    float rg[2][16], rl[2][16];

    #pragma unroll
    for (int bi = 0; bi < 2; ++bi) {
        const int b = t + 256 * bi;
        const float4* xv = reinterpret_cast<const float4*>(xr + 16 * b);
        float xe[17];
        {
            float4 v0 = xv[0], v1 = xv[1], v2 = xv[2], v3 = xv[3];
            xe[0]=v0.x;  xe[1]=v0.y;  xe[2]=v0.z;  xe[3]=v0.w;
            xe[4]=v1.x;  xe[5]=v1.y;  xe[6]=v1.z;  xe[7]=v1.w;
            xe[8]=v2.x;  xe[9]=v2.y;  xe[10]=v2.z; xe[11]=v2.w;
            xe[12]=v3.x; xe[13]=v3.y; xe[14]=v3.z; xe[15]=v3.w;
        }
        xe[16] = (b < 511) ? xr[16 * b + 16] : 0.f;

        float cg = 0.f, cl = 0.f;
        #pragma unroll
        for (int r = 0; r < 16; ++r) {
            const int j = 16 * b + r;
            float eg = 0.f, el = 0.f;
            if (j < NP) {
                const float prev = xe[r];
                const float nxt  = xe[r + 1];
                if (prev != 0.f) {
                    const float p = (nxt - prev) / prev;
                    eg = (p > 0.f) ?  p : 0.f;
                    el = (p < 0.f) ? -p : 0.f;
                }
            }
            cg = cg + eg;
            cl = cl + el;
            rg[bi][r] = cg;
            rl[bi][r] = cl;
        }
        T0g[b + (b >> 4)] = cg;
        T0l[b + (b >> 4)] = cl;
    }
    __syncthreads();

    if (t < 32) {
        float cg = 0.f, cl = 0.f;
        for (int s = 0; s < 16; ++s) {
            const int k = TS * t + s;
            cg = cg + T0g[k];
            cl = cl + T0l[k];
            S1g[k] = cg;
            S1l[k] = cl;
        }
        T1g[t] = cg; T1l[t] = cl;
    }
    __syncthreads();

    if (t < 2) {
        float cg = 0.f, cl = 0.f;
        for (int u = 0; u < 16; ++u) {
            cg = cg + T1g[16 * t + u];
            cl = cl + T1l[16 * t + u];
            S2g[16 * t + u] = cg;
            S2l[16 * t + u] = cl;
        }
        T2g[t] = cg; T2l[t] = cl;
    }
    __syncthreads();

    if (t == 0) {
        S3g[0] = T2g[0]; S3g[1] = T2g[0] + T2g[1];
        S3l[0] = T2l[0]; S3l[1] = T2l[0] + T2l[1];
    }
    __syncthreads();
    if (t >= 16 && t < 32) {
        S2g[t] = S2g[t] + S3g[0];
        S2l[t] = S2l[t] + S3l[0];
    }
    __syncthreads();
    for (int k = 16 + t; k < 512; k += BT) {
        const int c  = k >> 4;
        const int kp = k + (k >> 4);
        S1g[kp] = S1g[kp] + S2g[c - 1];
        S1l[kp] = S1l[kp] + S2l[c - 1];
    }
    __syncthreads();

    #pragma unroll
    for (int bi = 0; bi < 2; ++bi) {
        const int b = t + 256 * bi;
        float og = 0.f, ol = 0.f;
        if (b >= 1) {
            const int bp = (b - 1) + ((b - 1) >> 4);
            og = S1g[bp]; ol = S1l[bp];
        }
        float* __restrict__ cgp = &CG[TS * b];
        float* __restrict__ clp = &CL[TS * b];
        #pragma unroll
        for (int r = 0; r < 16; ++r) {
            cgp[r] = rg[bi][r] + og;
            clp[r] = rl[bi][r] + ol;
        }
    }
    __syncthreads();

    float* __restrict__ outr = out + (size_t)row * outW;
    for (int o = t; o < outW; o += BT) {
        const int j2 = o + wm1 - 1;
        const int i2 = TS * (j2 >> 4) + (j2 & 15);
        float cg1 = 0.f, cl1 = 0.f;
        if (o >= 1) {
            const int j1 = o - 1;
            const int i1 = TS * (j1 >> 4) + (j1 & 15);
            cg1 = CG[i1];
            cl1 = CL[i1];
        }
        const float a  = CG[i2] - cg1;
        const float bb = CL[i2] - cl1;
        float rs = 0.f;
        if (bb != 0.f) rs = a * __builtin_amdgcn_rcpf(bb);
        outr[o] = 1.f - __builtin_amdgcn_rcpf(1.f + rs);
    }
}

extern "C" void kernel_launch(void* const* d_in, const int* in_sizes, int n_in,
                              void* d_out, int out_size, void* d_ws, size_t ws_size,
                              hipStream_t stream) {
    const float* x   = (const float*)d_in[0];
    const int*   wsp = (const int*)d_in[1];
    float*       out = (float*)d_out;

    const int outW = out_size / ROWS;   // 8179
    const int wm1  = COLS - outW;       // == window_size - 1 (host-derived)
    dim3 grid(ROWS);                    // one block per row
    if (wm1 == 13) {
        rsi_reg_kernel<13><<<grid, dim3(BT6), 0, stream>>>(x, out, outW);
    } else {
        rsi_rwr_fallback<<<grid, dim3(BT), 0, stream>>>(x, wsp, out, outW);
    }
}

// Round 7
// 116.722 us; speedup vs baseline: 1.5484x; 1.0192x over previous
//
#include <hip/hip_runtime.h>

// RSI replicating jax-CPU cumsum via XLA ReduceWindowRewriter(base_length=16):
//   pad e[0..NP) with trailing zeros to 8192; reshape [512,16]
//   level-0: each 16-tile scanned SEQUENTIALLY; tile sums (512) -> recursively
//   [32,16] -> (32) -> [2,16] -> (2) -> len-2 scan; unwind adds ONE RN
//   exclusive outer offset per level.
//
// R1: LDS tile stride 16 -> 17 (bank conflicts 2.07e7 -> 2.33e6).
// R2: level-0 scan in regs; epilogue rcp-based. 66us/disp.
// R3/R4: register cumsum, 1 tile/thread; store scatter kept it ~98us.
// R5: outputs staged through padded LDS -> coalesced stores. ~38us.
// R6: coalesced load staging + LDS lifetime aliasing (SH). ~37us (+1us only;
//     load scatter was mostly hidden -- 4 instr/wave vs store side's 16).
// R7: occupancy + serial-path round:
//   (a) launch_bounds(512,8): VGPR cap 64 (R4 compiled to 36 -> safe).
//       LDS total 40424B -> exactly 4 blocks/CU = 32 waves/CU (was 3 blocks).
//   (b) B1+B2 merged into ONE wave-0 phase: B1 preloads its 16 T0 values
//       into regs (independent ds_reads) then scans in registers; an
//       intra-wave s_waitcnt lgkmcnt(0) replaces the B1->B2 __syncthreads
//       (producers+consumers all in wave 0; DS ops drain in order);
//       B2's four independent chains (g/l x 2 tiles) run on 4 lanes.
//       Per-chain RN add order untouched -> bit-identical. Barriers 6 -> 5.

constexpr int ROWS = 2048;
constexpr int COLS = 8192;
constexpr int NP   = COLS - 1;   // 8191 p-values; padded to 8192
constexpr int BT   = 256;        // fallback block size
constexpr int BT7  = 512;        // one 16-tile per thread
constexpr int TS   = 17;         // padded tile stride (16 data + 1 pad)

__device__ __forceinline__ int sidx(int f) {   // stage pad: +4 floats per 64
    return f + ((f >> 6) << 2);
}

// ---------------------------------------------------------------- R7 kernel
template<int WM1>
__global__ __launch_bounds__(BT7, 8)
void rsi_reg_kernel(const float* __restrict__ x,
                    float* __restrict__ out,
                    int outW)
{
    static_assert(WM1 >= 1 && WM1 <= 16, "phase-D mapping needs WM1<=16");
    // Multi-lifetime buffer:
    //   A0..A : staged input row, addr sidx(f), max 8191+508=8699
    //   B..C  : S1g = SH[0..544), S1l = SH[544..1088)  (raw level-1 scan)
    //   D..E  : XBUF, addr o + (o>>4), max 8178+511=8689
    __shared__ float SH[8704];
    __shared__ float T0g[544], T0l[544];   // level-0 tile sums (padded idx)
    __shared__ float T1g[32],  T1l[32];    // level-1 tile sums
    __shared__ float S2g[32],  S2l[32];    // level-2 scan values (raw)
    __shared__ float T2g[2],   T2l[2];     // level-2 tile sums (T2g[0]==S3g[0])
    // wave-boundary prev-tile cs[16-WM1..15]: slot w holds tile 64w+63
    __shared__ float BPg[7][WM1], BPl[7][WM1];

    float* const S1g = SH;                 // aliased lifetimes (see above)
    float* const S1l = SH + 544;

    const int row  = blockIdx.x;
    const int t    = threadIdx.x;          // == tile index b, 0..511
    const int lane = t & 63;
    const int w    = t >> 6;               // wave id 0..7
    const float* __restrict__ xr = x + (size_t)row * COLS;

    float rg[16], rl[16];                  // level-0 scan -> final cumsum

    // ---- phase A0: stage row into LDS, ideally coalesced
    #pragma unroll
    for (int m = 0; m < 4; ++m) {
        const int f = 4 * (t + 512 * m);   // f%4==0; f..f+3 in one 64-group
        const float4 v = *reinterpret_cast<const float4*>(xr + f);
        *reinterpret_cast<float4*>(&SH[sidx(f)]) = v;
    }
    __syncthreads();

    // ---- phase A: elements + level-0 sequential 16-tile scan (regs only)
    {
        float xe[17];
        {
            const int base = sidx(16 * t); // 16t..16t+15 share one 64-group
            #pragma unroll
            for (int q = 0; q < 4; ++q) {
                const float4 v = *reinterpret_cast<const float4*>(&SH[base + 4 * q]);
                xe[4*q+0]=v.x; xe[4*q+1]=v.y; xe[4*q+2]=v.z; xe[4*q+3]=v.w;
            }
            xe[16] = (t < 511) ? SH[sidx(16 * t + 16)] : 0.f; // unused j==NP
        }

        float cg = 0.f, cl = 0.f;
        #pragma unroll
        for (int r = 0; r < 16; ++r) {
            const int j = 16 * t + r;
            float eg = 0.f, el = 0.f;
            if (j < NP) {
                const float prev = xe[r];
                const float nxt  = xe[r + 1];
                if (prev != 0.f) {
                    const float p = (nxt - prev) / prev;   // IEEE f32 div (exact)
                    eg = (p > 0.f) ?  p : 0.f;
                    el = (p < 0.f) ? -p : 0.f;
                }
            }
            cg = cg + eg;          // RN; trailing pad adds +0 (bit-neutral)
            cl = cl + el;
            rg[r] = cg;
            rl[r] = cl;
        }
        T0g[t + (t >> 4)] = cg;    // padded T0 index
        T0l[t + (t >> 4)] = cl;
    }
    __syncthreads();               // staged input dead; SH becomes S1

    // ---- phase B (merged B1+B2, wave 0 only):
    //   B1: 64 independent chains (32 tiles x {g,l}), one per lane.
    //       Values preloaded to regs (independent ds_reads), then a
    //       16-register-add chain -- same RN order as before.
    //   B2: 4 independent chains (2 level-2 tiles x {g,l}) on lanes 0..3,
    //       after an intra-wave lgkmcnt(0) drain (no __syncthreads needed:
    //       T1 producers and consumers are all wave 0).
    if (t < 64) {
        const int  tt  = t & 31;
        const bool isl = (t >= 32);
        const float* __restrict__ src  = isl ? T0l : T0g;
        float* __restrict__       dstS = isl ? S1l : S1g;
        float* __restrict__       dstT = isl ? T1l : T1g;
        float v[16];
        #pragma unroll
        for (int s = 0; s < 16; ++s) v[s] = src[TS * tt + s];
        float c = 0.f;
        #pragma unroll
        for (int s = 0; s < 16; ++s) {
            c = c + v[s];                      // sequential RN chain (exact)
            dstS[TS * tt + s] = c;             // RAW scan value
        }
        dstT[tt] = c;

        asm volatile("s_waitcnt lgkmcnt(0)" ::: "memory");  // T1 visible in-wave

        if (t < 4) {                           // lanes 0..3: (g/l) x tile d
            const int  d    = t & 1;           // level-2 tile 0/1
            const bool isl2 = (t >= 2);
            const float* __restrict__ srcT = isl2 ? T1l : T1g;
            float* __restrict__       dstS2 = isl2 ? S2l : S2g;
            float* __restrict__       dstT2 = isl2 ? T2l : T2g;
            float u[16];
            #pragma unroll
            for (int q = 0; q < 16; ++q) u[q] = srcT[16 * d + q];
            float c2 = 0.f;
            #pragma unroll
            for (int q = 0; q < 16; ++q) {
                c2 = c2 + u[q];                // sequential RN chain (exact)
                dstS2[16 * d + q] = c2;        // raw scan values
            }
            dstT2[d] = c2;                     // T2g[0] == old S3g[0]
        }
    }
    __syncthreads();

    // ---- phase C: finalize cumsum IN REGISTERS.
    //      og = RN(S1raw[t-1] + RN(S2raw[c-1] (+ T2g[0] if c-1>=16)))
    //      == the old separate S2-finalize + S1-finalize RN sequence.
    //      Then rg += og (single RN add; t==0 adds +0.0, bit-neutral).
    {
        float og = 0.f, ol = 0.f;
        if (t >= 1) {
            const int bp = (t - 1) + ((t - 1) >> 4);
            og = S1g[bp]; ol = S1l[bp];        // raw level-1 scan
            const int c = (t - 1) >> 4;
            if (c >= 1) {
                float o2g = S2g[c - 1], o2l = S2l[c - 1];
                if (c - 1 >= 16) {             // level-3 offset (== S3g[0])
                    o2g = o2g + T2g[0];
                    o2l = o2l + T2l[0];
                }
                og = og + o2g;                 // RN(S1raw + finalizedS2)
                ol = ol + o2l;
            }
        }
        #pragma unroll
        for (int r = 0; r < 16; ++r) {
            rg[r] = rg[r] + og;
            rl[r] = rl[r] + ol;
        }
    }
    // boundary export: lane 63 of wave w publishes its tile tail for wave w+1
    if (lane == 63 && w < 7) {
        #pragma unroll
        for (int r = 16 - WM1; r < 16; ++r) {
            BPg[w][r - (16 - WM1)] = rg[r];
            BPl[w][r - (16 - WM1)] = rl[r];
        }
    }
    __syncthreads();               // S1 dead; SH becomes XBUF

    // ---- phase D: compute 16 outputs, stage into SH (padded, 2-way banks)
    //      o = 16t-(WM1-1)+k; cs[o+WM1-1]=rg[k]; cs[o-1]=rg[k-WM1] (k>=WM1)
    //      or prev-tile tail via shfl_up(1) / BP for lane 0 (k<WM1).
    {
        const int o0 = 16 * t - (WM1 - 1);
        #pragma unroll
        for (int k = 0; k < 16; ++k) {
            const int o = o0 + k;
            float cg1, cl1;
            if (k >= WM1) {
                cg1 = rg[k - WM1]; cl1 = rl[k - WM1];
            } else {
                cg1 = __shfl_up(rg[k + 16 - WM1], 1);
                cl1 = __shfl_up(rl[k + 16 - WM1], 1);
                if (lane == 0 && w > 0) {
                    cg1 = BPg[w - 1][k];
                    cl1 = BPl[w - 1][k];
                }
            }
            if (o < 1) { cg1 = 0.f; cl1 = 0.f; }   // o==0 uses zero prefix
            const float a  = rg[k] - cg1;
            const float bb = rl[k] - cl1;
            float rs = 0.f;
            if (bb != 0.f) rs = a * __builtin_amdgcn_rcpf(bb);
            const float v = 1.f - __builtin_amdgcn_rcpf(1.f + rs);
            if ((unsigned)o < (unsigned)outW) SH[o + (o >> 4)] = v;
        }
    }
    __syncthreads();

    // ---- phase E: coalesced readback + store
    float* __restrict__ outr = out + (size_t)row * outW;
    for (int o2 = t; o2 < outW; o2 += BT7) {
        outr[o2] = SH[o2 + (o2 >> 4)];
    }
}

// ------------------------------------------------- generic fallback (== R2)
__global__ __launch_bounds__(BT, 1)
void rsi_rwr_fallback(const float* __restrict__ x,
                      const int* __restrict__ wsp,
                      float* __restrict__ out,
                      int outW)
{
    __shared__ float CG[512 * TS], CL[512 * TS];
    __shared__ float T0g[544], T0l[544];
    __shared__ float S1g[544], S1l[544];
    __shared__ float T1g[32],  T1l[32];
    __shared__ float S2g[32],  S2l[32];
    __shared__ float T2g[2],   T2l[2];
    __shared__ float S3g[2],   S3l[2];

    const int row = blockIdx.x;
    const int t   = threadIdx.x;
    const int wm1 = *wsp - 1;
    const float* __restrict__ xr = x + (size_t)row * COLS;

    float rg[2][16], rl[2][16];

    #pragma unroll
    for (int bi = 0; bi < 2; ++bi) {
        const int b = t + 256 * bi;
        const float4* xv = reinterpret_cast<const float4*>(xr + 16 * b);
        float xe[17];
        {
            float4 v0 = xv[0], v1 = xv[1], v2 = xv[2], v3 = xv[3];
            xe[0]=v0.x;  xe[1]=v0.y;  xe[2]=v0.z;  xe[3]=v0.w;
            xe[4]=v1.x;  xe[5]=v1.y;  xe[6]=v1.z;  xe[7]=v1.w;
            xe[8]=v2.x;  xe[9]=v2.y;  xe[10]=v2.z; xe[11]=v2.w;
            xe[12]=v3.x; xe[13]=v3.y; xe[14]=v3.z; xe[15]=v3.w;
        }
        xe[16] = (b < 511) ? xr[16 * b + 16] : 0.f;

        float cg = 0.f, cl = 0.f;
        #pragma unroll
        for (int r = 0; r < 16; ++r) {
            const int j = 16 * b + r;
            float eg = 0.f, el = 0.f;
            if (j < NP) {
                const float prev = xe[r];
                const float nxt  = xe[r + 1];
                if (prev != 0.f) {
                    const float p = (nxt - prev) / prev;
                    eg = (p > 0.f) ?  p : 0.f;
                    el = (p < 0.f) ? -p : 0.f;
                }
            }
            cg = cg + eg;
            cl = cl + el;
            rg[bi][r] = cg;
            rl[bi][r] = cl;
        }
        T0g[b + (b >> 4)] = cg;
        T0l[b + (b >> 4)] = cl;
    }
    __syncthreads();

    if (t < 32) {
        float cg = 0.f, cl = 0.f;
        for (int s = 0; s < 16; ++s) {
            const int k = TS * t + s;
            cg = cg + T0g[k];
            cl = cl + T0l[k];
            S1g[k] = cg;
            S1l[k] = cl;
        }
        T1g[t] = cg; T1l[t] = cl;
    }
    __syncthreads();

    if (t < 2) {
        float cg = 0.f, cl = 0.f;
        for (int u = 0; u < 16; ++u) {
            cg = cg + T1g[16 * t + u];
            cl = cl + T1l[16 * t + u];
            S2g[16 * t + u] = cg;
            S2l[16 * t + u] = cl;
        }
        T2g[t] = cg; T2l[t] = cl;
    }
    __syncthreads();

    if (t == 0) {
        S3g[0] = T2g[0]; S3g[1] = T2g[0] + T2g[1];
        S3l[0] = T2l[0]; S3l[1] = T2l[0] + T2l[1];
    }
    __syncthreads();
    if (t >= 16 && t < 32) {
        S2g[t] = S2g[t] + S3g[0];
        S2l[t] = S2l[t] + S3l[0];
    }
    __syncthreads();
    for (int k = 16 + t; k < 512; k += BT) {
        const int c  = k >> 4;
        const int kp = k + (k >> 4);
        S1g[kp] = S1g[kp] + S2g[c - 1];
        S1l[kp] = S1l[kp] + S2l[c - 1];
    }
    __syncthreads();

    #pragma unroll
    for (int bi = 0; bi < 2; ++bi) {
        const int b = t + 256 * bi;
        float og = 0.f, ol = 0.f;
        if (b >= 1) {
            const int bp = (b - 1) + ((b - 1) >> 4);
            og = S1g[bp]; ol = S1l[bp];
        }
        float* __restrict__ cgp = &CG[TS * b];
        float* __restrict__ clp = &CL[TS * b];
        #pragma unroll
        for (int r = 0; r < 16; ++r) {
            cgp[r] = rg[bi][r] + og;
            clp[r] = rl[bi][r] + ol;
        }
    }
    __syncthreads();

    float* __restrict__ outr = out + (size_t)row * outW;
    for (int o = t; o < outW; o += BT) {
        const int j2 = o + wm1 - 1;
        const int i2 = TS * (j2 >> 4) + (j2 & 15);
        float cg1 = 0.f, cl1 = 0.f;
        if (o >= 1) {
            const int j1 = o - 1;
            const int i1 = TS * (j1 >> 4) + (j1 & 15);
            cg1 = CG[i1];
            cl1 = CL[i1];
        }
        const float a  = CG[i2] - cg1;
        const float bb = CL[i2] - cl1;
        float rs = 0.f;
        if (bb != 0.f) rs = a * __builtin_amdgcn_rcpf(bb);
        outr[o] = 1.f - __builtin_amdgcn_rcpf(1.f + rs);
    }
}

extern "C" void kernel_launch(void* const* d_in, const int* in_sizes, int n_in,
                              void* d_out, int out_size, void* d_ws, size_t ws_size,
                              hipStream_t stream) {
    const float* x   = (const float*)d_in[0];
    const int*   wsp = (const int*)d_in[1];
    float*       out = (float*)d_out;

    const int outW = out_size / ROWS;   // 8179
    const int wm1  = COLS - outW;       // == window_size - 1 (host-derived)
    dim3 grid(ROWS);                    // one block per row
    if (wm1 == 13) {
        rsi_reg_kernel<13><<<grid, dim3(BT7), 0, stream>>>(x, out, outW);
    } else {
        rsi_rwr_fallback<<<grid, dim3(BT), 0, stream>>>(x, wsp, out, outW);
    }
}